// Round 1
// baseline (760.920 us; speedup 1.0000x reference)
//
#include <hip/hip_runtime.h>
#include <hip/hip_bf16.h>

// Problem constants (CrossNetMixFuxiCTR): B=16384, D=2048, L=3, E=8, R=64
#define BDIM 16384
#define DDIM 2048
#define LNUM 3
#define ENUM 8
#define NP 24            // L*E (l,e) pairs

// GEMM tile
#define BM 256           // rows per block (4 waves x 64 rows)
#define BK 32            // f16 k-elements per iter (64 B/row)

typedef _Float16 f16x8 __attribute__((ext_vector_type(8)));
typedef _Float16 f16x4 __attribute__((ext_vector_type(4)));
typedef float f32x4 __attribute__((ext_vector_type(4)));

// ------- convert U,V -> Wh f16, layout [p=24][128 rows: 64 U then 64 V][D] -------
__global__ void cvt_w_kernel(const float* __restrict__ U, const float* __restrict__ V,
                             _Float16* __restrict__ Wh) {
    size_t f = (size_t)blockIdx.x * blockDim.x + threadIdx.x;   // float4 index
    size_t elem = f * 4;
    int d   = (int)(elem & (DDIM - 1));
    int row = (int)((elem >> 11) & 127);   // /2048 % 128
    int p   = (int)(elem >> 18);           // /(2048*128)
    const float* src = (row < 64)
        ? (U + ((size_t)(p * 64 + row) * DDIM + d))
        : (V + ((size_t)(p * 64 + (row - 64)) * DDIM + d));
    float4 v = *(const float4*)src;
    f16x4 h = { (_Float16)v.x, (_Float16)v.y, (_Float16)v.z, (_Float16)v.w };
    ((f16x4*)Wh)[f] = h;
}

// ---- fused: gate logits G[j][b] = X0[b].Wg[j] (fp32)  +  X0 -> X0h f16 conversion ----
// Occupancy fix vs previous rev: 32 rows/block (grid 512 = 2 blocks/CU = 8 waves/CU,
// was 64 rows/block -> 1 block/CU = 1 wave/SIMD, pure latency serialization).
// Each thread: 2 rows (rq, rq+16), 1/16 of k (q = tid&15).
// Wg staged in LDS in 256-float k-chunks (24 KB); w-reads are 16-addr x 4-lane broadcast
// (2-way bank aliasing = free). acc[2][24] = 48 VGPRs; __launch_bounds__(256,2) gives the
// 128-VGPR budget (the old (256,4)=64-VGPR cap risked spill with 48 acc regs).
__global__ __launch_bounds__(256, 2) void gate_kernel(
    const float* __restrict__ X0, const float* __restrict__ Wg,
    float* __restrict__ G, _Float16* __restrict__ X0h) {
    __shared__ float Wgs[NP * 256];   // 24 KB
    const int tid = (int)threadIdx.x;
    const int rq  = tid >> 4;          // 0..15
    const int q   = tid & 15;          // k-slice
    const int r0  = blockIdx.x * 32 + rq;
    const int r1  = r0 + 16;

    float acc[2][NP];
#pragma unroll
    for (int r = 0; r < 2; ++r)
#pragma unroll
        for (int j = 0; j < NP; ++j) acc[r][j] = 0.f;

    const float4* x0p = (const float4*)(X0 + (size_t)r0 * DDIM);
    const float4* x1p = (const float4*)(X0 + (size_t)r1 * DDIM);
    f16x4* h0p = (f16x4*)(X0h + (size_t)r0 * DDIM);
    f16x4* h1p = (f16x4*)(X0h + (size_t)r1 * DDIM);

    for (int k0 = 0; k0 < DDIM; k0 += 256) {
        __syncthreads();
        // stage Wg[0:24][k0:k0+256) -> LDS: 1536 float4 by 256 threads
#pragma unroll
        for (int t = tid; t < NP * 64; t += 256)
            ((float4*)Wgs)[t] =
                ((const float4*)Wg)[(size_t)(t >> 6) * (DDIM / 4) + (k0 >> 2) + (t & 63)];
        __syncthreads();
#pragma unroll
        for (int i = 0; i < 4; ++i) {
            int f4 = i * 16 + q;                // float4 index within chunk [0,64)
            int gc = (k0 >> 2) + f4;            // global float4 column
            float4 x0 = x0p[gc];
            float4 x1 = x1p[gc];
            f16x4 h0 = { (_Float16)x0.x, (_Float16)x0.y, (_Float16)x0.z, (_Float16)x0.w };
            f16x4 h1 = { (_Float16)x1.x, (_Float16)x1.y, (_Float16)x1.z, (_Float16)x1.w };
            h0p[gc] = h0;
            h1p[gc] = h1;
#pragma unroll
            for (int j = 0; j < NP; ++j) {
                float4 w = ((const float4*)(Wgs + j * 256))[f4];
                acc[0][j] += x0.x * w.x + x0.y * w.y + x0.z * w.z + x0.w * w.w;
                acc[1][j] += x1.x * w.x + x1.y * w.y + x1.z * w.z + x1.w * w.w;
            }
        }
    }
    // reduce over the 16 k-slices (lanes differing in bits 0..3)
#pragma unroll
    for (int r = 0; r < 2; ++r)
#pragma unroll
        for (int j = 0; j < NP; ++j) {
            float v = acc[r][j];
            v += __shfl_xor(v, 1);
            v += __shfl_xor(v, 2);
            v += __shfl_xor(v, 4);
            v += __shfl_xor(v, 8);
            if (q == 0) G[(size_t)j * BDIM + (r == 0 ? r0 : r1)] = v;
        }
}

// ---------------- MFMA GEMM + in-wave bilinear reduction ----------------
// Block: 256 thr (4 waves). Tile: 256 rows x 128 cols (one (l,e): cols 0-63 = PU, 64-127 = PV).
// Wave w computes rows [w*64, w*64+64) x all 128 cols -> 4x8 tiles of 16x16x32 f16 MFMA,
// 32 MFMA per 12 ds_read_b128 per k-iter (0.375 reads/MFMA).
// LDS XOR swizzle: position chunk c of row r holds global k-chunk c ^ sigma(r),
// sigma(r) = (r>>1)&3 -> read groups are 2-way per bank (free), kills the 4-way conflicts.
// T[p][m] = sum_r PU[m][r]*PV[m][r] via in-lane acc[mi][ni]*acc[mi][ni+4] + butterfly.
__global__ __launch_bounds__(256, 2) void gemm_t_kernel(
    const _Float16* __restrict__ Ah,   // [BDIM][DDIM] f16
    const _Float16* __restrict__ Bh,   // [NP][128][DDIM] f16
    float* __restrict__ T)             // [NP][BDIM]
{
    const int p    = blockIdx.y;
    const int m0   = blockIdx.x * BM;
    const int tid  = (int)threadIdx.x;
    const int wave = tid >> 6;
    const int lane = tid & 63;
    const int mlane = lane & 15;
    const int quad  = lane >> 4;

    __shared__ _Float16 As[BM * BK];    // 16 KB
    __shared__ _Float16 Bs[128 * BK];   // 8 KB

    const _Float16* Bp = Bh + (size_t)p * 128 * DDIM;

    f32x4 acc[4][8];
#pragma unroll
    for (int i = 0; i < 4; ++i)
#pragma unroll
        for (int j = 0; j < 8; ++j) acc[i][j] = (f32x4){0.f, 0.f, 0.f, 0.f};

    const int srow = lane >> 2;                              // 0..15 within 16-row chunk
    const int scol = ((lane & 3) ^ ((lane >> 3) & 3)) * 8;   // swizzled global f16 col
    const int sw   = (mlane >> 1) & 3;                       // sigma(row) for reads

    for (int k0 = 0; k0 < DDIM; k0 += BK) {
        __syncthreads();   // previous iter's LDS reads done before overwrite
#pragma unroll
        for (int q = 0; q < 4; ++q) {                        // A: 64 own rows
            int r16 = wave * 64 + q * 16;
            const _Float16* ga = Ah + (size_t)(m0 + r16 + srow) * DDIM + k0 + scol;
            __builtin_amdgcn_global_load_lds(
                (const __attribute__((address_space(1))) void*)ga,
                (__attribute__((address_space(3))) void*)&As[r16 * BK], 16, 0, 0);
        }
#pragma unroll
        for (int q = 0; q < 2; ++q) {                        // B: 32 rows per wave
            int r16 = wave * 32 + q * 16;
            const _Float16* gb = Bp + (size_t)(r16 + srow) * DDIM + k0 + scol;
            __builtin_amdgcn_global_load_lds(
                (const __attribute__((address_space(1))) void*)gb,
                (__attribute__((address_space(3))) void*)&Bs[r16 * BK], 16, 0, 0);
        }
        __syncthreads();   // drains vmcnt -> staged data visible

        f16x8 aF[4], bF[8];
#pragma unroll
        for (int mi = 0; mi < 4; ++mi)
            aF[mi] = *(const f16x8*)&As[(wave * 64 + mi * 16 + mlane) * BK + ((quad ^ sw) * 8)];
#pragma unroll
        for (int ni = 0; ni < 8; ++ni)
            bF[ni] = *(const f16x8*)&Bs[(ni * 16 + mlane) * BK + ((quad ^ sw) * 8)];
#pragma unroll
        for (int mi = 0; mi < 4; ++mi)
#pragma unroll
            for (int ni = 0; ni < 8; ++ni)
                acc[mi][ni] = __builtin_amdgcn_mfma_f32_16x16x32_f16(
                    aF[mi], bF[ni], acc[mi][ni], 0, 0, 0);
    }

    // C/D layout: col = lane&15, row = quad*4 + reg. PU col r at ni=r/16, PV at ni+4 (same lane).
#pragma unroll
    for (int mi = 0; mi < 4; ++mi) {
#pragma unroll
        for (int j = 0; j < 4; ++j) {
            float tp = 0.f;
#pragma unroll
            for (int ni = 0; ni < 4; ++ni)
                tp += acc[mi][ni][j] * acc[mi][ni + 4][j];
            tp += __shfl_xor(tp, 1);
            tp += __shfl_xor(tp, 2);
            tp += __shfl_xor(tp, 4);
            tp += __shfl_xor(tp, 8);
            if (mlane == 0) {
                int m = wave * 64 + mi * 16 + quad * 4 + j;
                T[(size_t)p * BDIM + (m0 + m)] = tp;
            }
        }
    }
}

// ---------------- per-row scalar recurrence + scaled write-out (reads X0h f16) ----------------
__global__ void epilogue_kernel(const _Float16* __restrict__ X0h,
                                const float* __restrict__ T,
                                const float* __restrict__ G,
                                const float* __restrict__ bg,
                                float* __restrict__ out) {
    __shared__ float s_sh[16];
    const int b0 = blockIdx.x * 16;
    const int tid = (int)threadIdx.x;
    if (tid < 16) {
        int b = b0 + tid;
        float s = 1.f;
#pragma unroll
        for (int l = 0; l < LNUM; ++l) {
            float logit[ENUM];
            float mx = -1e30f;
#pragma unroll
            for (int e = 0; e < ENUM; ++e) {
                int j = l * ENUM + e;
                float g = s * G[(size_t)j * BDIM + b] + bg[j];
                logit[e] = g;
                mx = fmaxf(mx, g);
            }
            float den = 0.f, num = 0.f;
            float s2 = s * s;
#pragma unroll
            for (int e = 0; e < ENUM; ++e) {
                int j = l * ENUM + e;
                float w = __expf(logit[e] - mx);
                den += w;
                num += w * (s2 * T[(size_t)j * BDIM + b]);
            }
            s += num / den;
        }
        s_sh[tid] = s;
    }
    __syncthreads();
    const int nf4 = DDIM / 4;   // 512 float4 per row
    for (int idx = tid; idx < 16 * nf4; idx += 256) {
        int r = idx >> 9;
        int c = idx & (nf4 - 1);
        float s = s_sh[r];
        f16x4 h = ((const f16x4*)(X0h + (size_t)(b0 + r) * DDIM))[c];
        float4 x = { s * (float)h[0], s * (float)h[1], s * (float)h[2], s * (float)h[3] };
        ((float4*)(out + (size_t)(b0 + r) * DDIM))[c] = x;
    }
}

extern "C" void kernel_launch(void* const* d_in, const int* in_sizes, int n_in,
                              void* d_out, int out_size, void* d_ws, size_t ws_size,
                              hipStream_t stream) {
    const float* X0 = (const float*)d_in[0];
    const float* U  = (const float*)d_in[1];
    const float* V  = (const float*)d_in[2];
    const float* Wg = (const float*)d_in[3];
    const float* bg = (const float*)d_in[4];
    float* out = (float*)d_out;

    // workspace layout (~82.8 MB)
    char* ws = (char*)d_ws;
    _Float16* X0h = (_Float16*)ws;                                   // 16384*2048*2 = 67108864
    _Float16* Wh  = (_Float16*)(ws + 67108864ull);                   // 24*128*2048*2 = 12582912
    float* T      = (float*)(ws + 67108864ull + 12582912ull);        // 24*16384*4 = 1572864
    float* G      = (float*)(ws + 67108864ull + 12582912ull + 1572864ull);

    cvt_w_kernel<<<dim3((NP * 128 * DDIM / 4) / 256), dim3(256), 0, stream>>>(U, V, Wh);
    gate_kernel<<<dim3(BDIM / 32), dim3(256), 0, stream>>>(X0, Wg, G, X0h);
    gemm_t_kernel<<<dim3(BDIM / BM, NP), dim3(256), 0, stream>>>(X0h, Wh, T);
    epilogue_kernel<<<dim3(BDIM / 16), dim3(256), 0, stream>>>(X0h, T, G, bg, out);
}

// Round 2
// 524.122 us; speedup vs baseline: 1.4518x; 1.4518x over previous
//
#include <hip/hip_runtime.h>
#include <hip/hip_bf16.h>

// Problem constants (CrossNetMixFuxiCTR): B=16384, D=2048, L=3, E=8, R=64
#define BDIM 16384
#define DDIM 2048
#define LNUM 3
#define ENUM 8
#define NP 24            // L*E (l,e) pairs
#define NPG 25           // NP + 1 gate slice (p==NP computes G = X0h . Wgh^T)

// GEMM tile
#define BM 256           // rows per block (4 waves x 64 rows)
#define BK 32            // f16 k-elements per iter (64 B/row)

typedef _Float16 f16x8 __attribute__((ext_vector_type(8)));
typedef _Float16 f16x4 __attribute__((ext_vector_type(4)));
typedef float f32x4 __attribute__((ext_vector_type(4)));

// ------- convert U,V -> Wh f16, layout [p=24][128 rows: 64 U then 64 V][D] -------
__global__ void cvt_w_kernel(const float* __restrict__ U, const float* __restrict__ V,
                             _Float16* __restrict__ Wh) {
    size_t f = (size_t)blockIdx.x * blockDim.x + threadIdx.x;   // float4 index
    size_t elem = f * 4;
    int d   = (int)(elem & (DDIM - 1));
    int row = (int)((elem >> 11) & 127);   // /2048 % 128
    int p   = (int)(elem >> 18);           // /(2048*128)
    const float* src = (row < 64)
        ? (U + ((size_t)(p * 64 + row) * DDIM + d))
        : (V + ((size_t)(p * 64 + (row - 64)) * DDIM + d));
    float4 v = *(const float4*)src;
    f16x4 h = { (_Float16)v.x, (_Float16)v.y, (_Float16)v.z, (_Float16)v.w };
    ((f16x4*)Wh)[f] = h;
}

// ------- convert Wg (24 x 2048 f32) -> Wgh f16 -------
__global__ void cvt_wg_kernel(const float* __restrict__ Wg, _Float16* __restrict__ Wgh) {
    int f = (int)(blockIdx.x * blockDim.x + threadIdx.x);   // 12288 float4
    float4 v = ((const float4*)Wg)[f];
    f16x4 h = { (_Float16)v.x, (_Float16)v.y, (_Float16)v.z, (_Float16)v.w };
    ((f16x4*)Wgh)[f] = h;
}

// ------- convert X0 f32 -> X0h f16 (memory-bound, ~30 us) -------
__global__ void cvt_x_kernel(const float* __restrict__ X0, _Float16* __restrict__ X0h) {
    size_t f = (size_t)blockIdx.x * blockDim.x + threadIdx.x;   // float4 index
    float4 v = ((const float4*)X0)[f];
    f16x4 h = { (_Float16)v.x, (_Float16)v.y, (_Float16)v.z, (_Float16)v.w };
    ((f16x4*)X0h)[f] = h;
}

// ---------------- MFMA GEMM + in-wave bilinear reduction ----------------
// Block: 256 thr (4 waves). Tile: 256 rows x 128 cols (one (l,e): cols 0-63 = PU, 64-127 = PV).
// Wave w computes rows [w*64, w*64+64) x all 128 cols -> 4x8 tiles of 16x16x32 f16 MFMA,
// 32 MFMA per 12 ds_read_b128 per k-iter (0.375 reads/MFMA).
// LDS XOR swizzle: position chunk c of row r holds global k-chunk c ^ sigma(r),
// sigma(r) = (r>>1)&3 -> read groups are 2-way per bank (free), kills the 4-way conflicts.
// T[p][m] = sum_r PU[m][r]*PV[m][r] via in-lane acc[mi][ni]*acc[mi][ni+4] + butterfly.
// p == NP is the GATE slice: B rows 0..23 are Wgh (rows >=24 remapped, cols discarded);
// epilogue writes raw C cols 0..23 to G[col][m] instead of the bilinear reduce.
// (Replaces the old standalone gate_kernel, which was regalloc-fragile: its acc[2][24]
//  spilled to scratch -> ~800 MB of HBM spill traffic, 353 us.)
__global__ __launch_bounds__(256, 2) void gemm_t_kernel(
    const _Float16* __restrict__ Ah,   // [BDIM][DDIM] f16
    const _Float16* __restrict__ Bh,   // [NP][128][DDIM] f16
    const _Float16* __restrict__ Wgh,  // [NP][DDIM] f16 (gate vectors)
    float* __restrict__ T,             // [NP][BDIM]
    float* __restrict__ G)             // [NP][BDIM] gate logits (f32 accum)
{
    const int p    = blockIdx.y;
    const int m0   = blockIdx.x * BM;
    const int tid  = (int)threadIdx.x;
    const int wave = tid >> 6;
    const int lane = tid & 63;
    const int mlane = lane & 15;
    const int quad  = lane >> 4;

    __shared__ _Float16 As[BM * BK];    // 16 KB
    __shared__ _Float16 Bs[128 * BK];   // 8 KB

    f32x4 acc[4][8];
#pragma unroll
    for (int i = 0; i < 4; ++i)
#pragma unroll
        for (int j = 0; j < 8; ++j) acc[i][j] = (f32x4){0.f, 0.f, 0.f, 0.f};

    const int srow = lane >> 2;                              // 0..15 within 16-row chunk
    const int scol = ((lane & 3) ^ ((lane >> 3) & 3)) * 8;   // swizzled global f16 col
    const int sw   = (mlane >> 1) & 3;                       // sigma(row) for reads

    const bool gate = (p == NP);
    const _Float16* Bp = gate ? Wgh : (Bh + (size_t)p * 128 * DDIM);

    for (int k0 = 0; k0 < DDIM; k0 += BK) {
        __syncthreads();   // previous iter's LDS reads done before overwrite
#pragma unroll
        for (int q = 0; q < 4; ++q) {                        // A: 64 own rows
            int r16 = wave * 64 + q * 16;
            const _Float16* ga = Ah + (size_t)(m0 + r16 + srow) * DDIM + k0 + scol;
            __builtin_amdgcn_global_load_lds(
                (const __attribute__((address_space(1))) void*)ga,
                (__attribute__((address_space(3))) void*)&As[r16 * BK], 16, 0, 0);
        }
#pragma unroll
        for (int q = 0; q < 2; ++q) {                        // B: 32 rows per wave
            int r16 = wave * 32 + q * 16;
            int r   = r16 + srow;
            // gate slice has only 24 valid B rows; remap r>=24 to a valid row (cols discarded)
            int rb  = (gate && r >= NP) ? (r & 15) : r;
            const _Float16* gb = Bp + (size_t)rb * DDIM + k0 + scol;
            __builtin_amdgcn_global_load_lds(
                (const __attribute__((address_space(1))) void*)gb,
                (__attribute__((address_space(3))) void*)&Bs[r16 * BK], 16, 0, 0);
        }
        __syncthreads();   // drains vmcnt -> staged data visible

        f16x8 aF[4], bF[8];
#pragma unroll
        for (int mi = 0; mi < 4; ++mi)
            aF[mi] = *(const f16x8*)&As[(wave * 64 + mi * 16 + mlane) * BK + ((quad ^ sw) * 8)];
#pragma unroll
        for (int ni = 0; ni < 8; ++ni)
            bF[ni] = *(const f16x8*)&Bs[(ni * 16 + mlane) * BK + ((quad ^ sw) * 8)];
#pragma unroll
        for (int mi = 0; mi < 4; ++mi)
#pragma unroll
            for (int ni = 0; ni < 8; ++ni)
                acc[mi][ni] = __builtin_amdgcn_mfma_f32_16x16x32_f16(
                    aF[mi], bF[ni], acc[mi][ni], 0, 0, 0);
    }

    // C/D layout: col = lane&15 (B-row), row = quad*4 + reg (A-row within 16-tile).
    if (!gate) {
        // PU col r at ni=r/16, PV at ni+4 (same lane).
#pragma unroll
        for (int mi = 0; mi < 4; ++mi) {
#pragma unroll
            for (int j = 0; j < 4; ++j) {
                float tp = 0.f;
#pragma unroll
                for (int ni = 0; ni < 4; ++ni)
                    tp += acc[mi][ni][j] * acc[mi][ni + 4][j];
                tp += __shfl_xor(tp, 1);
                tp += __shfl_xor(tp, 2);
                tp += __shfl_xor(tp, 4);
                tp += __shfl_xor(tp, 8);
                if (mlane == 0) {
                    int m = wave * 64 + mi * 16 + quad * 4 + j;
                    T[(size_t)p * BDIM + (m0 + m)] = tp;
                }
            }
        }
    } else {
        // gate logits: C[m][col] = X0h[m].Wgh[col], col < 24 -> G[col][m]
#pragma unroll
        for (int mi = 0; mi < 4; ++mi)
#pragma unroll
            for (int ni = 0; ni < 2; ++ni) {
                int col = ni * 16 + mlane;
                if (col < NP) {
#pragma unroll
                    for (int j = 0; j < 4; ++j) {
                        int m = wave * 64 + mi * 16 + quad * 4 + j;
                        G[(size_t)col * BDIM + (m0 + m)] = acc[mi][ni][j];
                    }
                }
            }
    }
}

// ---------------- per-row scalar recurrence + scaled write-out (reads X0h f16) ----------------
__global__ void epilogue_kernel(const _Float16* __restrict__ X0h,
                                const float* __restrict__ T,
                                const float* __restrict__ G,
                                const float* __restrict__ bg,
                                float* __restrict__ out) {
    __shared__ float s_sh[16];
    const int b0 = blockIdx.x * 16;
    const int tid = (int)threadIdx.x;
    if (tid < 16) {
        int b = b0 + tid;
        float s = 1.f;
#pragma unroll
        for (int l = 0; l < LNUM; ++l) {
            float logit[ENUM];
            float mx = -1e30f;
#pragma unroll
            for (int e = 0; e < ENUM; ++e) {
                int j = l * ENUM + e;
                float g = s * G[(size_t)j * BDIM + b] + bg[j];
                logit[e] = g;
                mx = fmaxf(mx, g);
            }
            float den = 0.f, num = 0.f;
            float s2 = s * s;
#pragma unroll
            for (int e = 0; e < ENUM; ++e) {
                int j = l * ENUM + e;
                float w = __expf(logit[e] - mx);
                den += w;
                num += w * (s2 * T[(size_t)j * BDIM + b]);
            }
            s += num / den;
        }
        s_sh[tid] = s;
    }
    __syncthreads();
    const int nf4 = DDIM / 4;   // 512 float4 per row
    for (int idx = tid; idx < 16 * nf4; idx += 256) {
        int r = idx >> 9;
        int c = idx & (nf4 - 1);
        float s = s_sh[r];
        f16x4 h = ((const f16x4*)(X0h + (size_t)(b0 + r) * DDIM))[c];
        float4 x = { s * (float)h[0], s * (float)h[1], s * (float)h[2], s * (float)h[3] };
        ((float4*)(out + (size_t)(b0 + r) * DDIM))[c] = x;
    }
}

extern "C" void kernel_launch(void* const* d_in, const int* in_sizes, int n_in,
                              void* d_out, int out_size, void* d_ws, size_t ws_size,
                              hipStream_t stream) {
    const float* X0 = (const float*)d_in[0];
    const float* U  = (const float*)d_in[1];
    const float* V  = (const float*)d_in[2];
    const float* Wg = (const float*)d_in[3];
    const float* bg = (const float*)d_in[4];
    float* out = (float*)d_out;

    // workspace layout (~82.9 MB)
    char* ws = (char*)d_ws;
    _Float16* X0h = (_Float16*)ws;                                   // 16384*2048*2 = 67108864
    _Float16* Wh  = (_Float16*)(ws + 67108864ull);                   // 24*128*2048*2 = 12582912
    _Float16* Wgh = (_Float16*)(ws + 79691776ull);                   // 24*2048*2 = 98304
    float* T      = (float*)(ws + 79790080ull);                      // 24*16384*4 = 1572864
    float* G      = (float*)(ws + 81362944ull);                      // 24*16384*4 = 1572864

    cvt_w_kernel<<<dim3((NP * 128 * DDIM / 4) / 256), dim3(256), 0, stream>>>(U, V, Wh);
    cvt_wg_kernel<<<dim3((NP * DDIM / 4) / 256), dim3(256), 0, stream>>>(Wg, Wgh);
    cvt_x_kernel<<<dim3((BDIM * DDIM / 4) / 256), dim3(256), 0, stream>>>(X0, X0h);
    gemm_t_kernel<<<dim3(BDIM / BM, NPG), dim3(256), 0, stream>>>(X0h, Wh, Wgh, T, G);
    epilogue_kernel<<<dim3(BDIM / 16), dim3(256), 0, stream>>>(X0h, T, G, bg, out);
}

// Round 3
// 492.246 us; speedup vs baseline: 1.5458x; 1.0648x over previous
//
#include <hip/hip_runtime.h>
#include <hip/hip_bf16.h>

// Problem constants (CrossNetMixFuxiCTR): B=16384, D=2048, L=3, E=8, R=64
#define BDIM 16384
#define DDIM 2048
#define LNUM 3
#define ENUM 8
#define NP 24            // L*E (l,e) pairs

// GEMM tile (8-wave pipelined template)
#define BM 256           // A rows per block
#define BK 64            // f16 k-elements per tile (128 B/row)
#define NT (DDIM / BK)   // 32 K-tiles

typedef _Float16 f16x8 __attribute__((ext_vector_type(8)));
typedef _Float16 f16x4 __attribute__((ext_vector_type(4)));
typedef float f32x4 __attribute__((ext_vector_type(4)));

// ------- convert U,V -> Wh f16, layout [p=24][128 rows: 64 U then 64 V][D] -------
__global__ void cvt_w_kernel(const float* __restrict__ U, const float* __restrict__ V,
                             _Float16* __restrict__ Wh) {
    size_t f = (size_t)blockIdx.x * blockDim.x + threadIdx.x;   // float4 index
    size_t elem = f * 4;
    int d   = (int)(elem & (DDIM - 1));
    int row = (int)((elem >> 11) & 127);   // /2048 % 128
    int p   = (int)(elem >> 18);           // /(2048*128)
    const float* src = (row < 64)
        ? (U + ((size_t)(p * 64 + row) * DDIM + d))
        : (V + ((size_t)(p * 64 + (row - 64)) * DDIM + d));
    float4 v = *(const float4*)src;
    f16x4 h = { (_Float16)v.x, (_Float16)v.y, (_Float16)v.z, (_Float16)v.w };
    ((f16x4*)Wh)[f] = h;
}

// ------- convert Wg (24 x 2048 f32) -> Wgh f16 -------
__global__ void cvt_wg_kernel(const float* __restrict__ Wg, _Float16* __restrict__ Wgh) {
    int f = (int)(blockIdx.x * blockDim.x + threadIdx.x);   // 12288 float4
    float4 v = ((const float4*)Wg)[f];
    f16x4 h = { (_Float16)v.x, (_Float16)v.y, (_Float16)v.z, (_Float16)v.w };
    ((f16x4*)Wgh)[f] = h;
}

// ------- convert X0 f32 -> X0h f16 (memory-bound) -------
__global__ void cvt_x_kernel(const float* __restrict__ X0, _Float16* __restrict__ X0h) {
    size_t f = (size_t)blockIdx.x * blockDim.x + threadIdx.x;   // float4 index
    float4 v = ((const float4*)X0)[f];
    f16x4 h = { (_Float16)v.x, (_Float16)v.y, (_Float16)v.z, (_Float16)v.w };
    ((f16x4*)X0h)[f] = h;
}

// ---------------- pipelined MFMA GEMM + in-wave bilinear reduction ----------------
// 512 thr = 8 waves (wm = wave>>1 in 0..3, wc = wave&1). Tile: 256 rows x 256 cols,
// where cols = TWO p-slices stacked (slice p = 2*by + wc, 128 cols each: 0-63 PU, 64-127 PV).
// Wave (wm,wc): rows [wm*64,+64) x full 128 cols of its slice -> acc[4][8], in-wave bilinear.
// Schedule (T3+T4+T5): double-buffered 128 KiB LDS, 2 K-tiles in flight,
// counted s_waitcnt vmcnt(8) (8 global_load_lds per thread per tile) + raw s_barrier;
// never drains vmcnt to 0 in the main loop. setprio(1) around MFMA clusters.
// LDS swizzle: chunk c (16B) of row r holds global chunk c ^ (r&7); applied on the
// pre-swizzled GLOBAL source address (linear LDS dest, rule #21) and on the ds_read addr.
// Read conflict: 16 consecutive rows x same logical chunk -> 8 distinct 16B slots = 2-way (free).
// by == 12 is the GATE block: wc==0 computes G = X0h . Wgh^T (cols 0..23), wc==1 discarded.
__global__ __launch_bounds__(512, 2) void gemm_t_kernel(
    const _Float16* __restrict__ Ah,   // [BDIM][DDIM] f16
    const _Float16* __restrict__ Bh,   // [NP][128][DDIM] f16
    const _Float16* __restrict__ Wgh,  // [NP][DDIM] f16 (gate vectors)
    float* __restrict__ T,             // [NP][BDIM]
    float* __restrict__ G)             // [NP][BDIM] gate logits (f32 accum)
{
    const int by   = blockIdx.y;          // 0..11 slice pairs, 12 = gate
    const int m0   = blockIdx.x * BM;
    const int tid  = (int)threadIdx.x;
    const int wave = tid >> 6;
    const int lane = tid & 63;
    const int wm   = wave >> 1;           // 0..3 row quadrant
    const int wc   = wave & 1;            // 0/1 slice within pair
    const int mlane = lane & 15;
    const int quad  = lane >> 4;
    const bool gateblk = (by == 12);

    // [buf][A/B][256 rows * 64 f16] = 128 KiB
    __shared__ _Float16 Ls[2][2][BM * BK];

    // ---- per-thread staging source pointers (pre-swizzled global addresses) ----
    const _Float16* aptr[4];
    const _Float16* bptr[4];
#pragma unroll
    for (int q = 0; q < 4; ++q) {
        int idx = q * 512 + tid;          // 16B-chunk index 0..2047
        int row = idx >> 3;               // 0..255
        int c   = idx & 7;
        int col = ((c ^ (row & 7)) * 8);  // swizzled f16 column within the 64-wide tile
        aptr[q] = Ah + (size_t)(m0 + row) * DDIM + col;
        int s = row >> 7;                 // which slice of the pair
        int brow = row & 127;
        const _Float16* base;
        int br;
        if (gateblk) {
            base = Wgh;
            br = (s == 0 && brow < NP) ? brow : (brow & 15);   // keep addresses valid
        } else {
            base = Bh + (size_t)(2 * by + s) * 128 * DDIM;
            br = brow;
        }
        bptr[q] = base + (size_t)br * DDIM + col;
    }

    f32x4 acc[4][8];
#pragma unroll
    for (int i = 0; i < 4; ++i)
#pragma unroll
        for (int j = 0; j < 8; ++j) acc[i][j] = (f32x4){0.f, 0.f, 0.f, 0.f};

    // ---- prologue: stage tiles 0 and 1 ----
#pragma unroll
    for (int tt = 0; tt < 2; ++tt) {
#pragma unroll
        for (int q = 0; q < 4; ++q)
            __builtin_amdgcn_global_load_lds(
                (const __attribute__((address_space(1))) void*)(aptr[q] + tt * BK),
                (__attribute__((address_space(3))) void*)&Ls[tt][0][(q * 512 + wave * 64) * 8],
                16, 0, 0);
#pragma unroll
        for (int q = 0; q < 4; ++q)
            __builtin_amdgcn_global_load_lds(
                (const __attribute__((address_space(1))) void*)(bptr[q] + tt * BK),
                (__attribute__((address_space(3))) void*)&Ls[tt][1][(q * 512 + wave * 64) * 8],
                16, 0, 0);
    }

    int cur = 0;
    for (int t = 0; t < NT; ++t) {
        // own tile-t loads landed (8 of tile t+1 stay in flight); barrier promotes to block-wide
        if (t < NT - 1) asm volatile("s_waitcnt vmcnt(8)" ::: "memory");
        else            asm volatile("s_waitcnt vmcnt(0)" ::: "memory");
        __builtin_amdgcn_s_barrier();

        const _Float16* Asc = &Ls[cur][0][0];
        const _Float16* Bsc = &Ls[cur][1][0];
#pragma unroll
        for (int ks = 0; ks < 2; ++ks) {
            f16x8 aF[4], bF[8];
#pragma unroll
            for (int mi = 0; mi < 4; ++mi) {
                int row = wm * 64 + mi * 16 + mlane;
                aF[mi] = *(const f16x8*)&Asc[row * BK + (((ks * 4 + quad) ^ (row & 7)) * 8)];
            }
#pragma unroll
            for (int ni = 0; ni < 8; ++ni) {
                int row = wc * 128 + ni * 16 + mlane;
                bF[ni] = *(const f16x8*)&Bsc[row * BK + (((ks * 4 + quad) ^ (row & 7)) * 8)];
            }
            __builtin_amdgcn_s_setprio(1);
#pragma unroll
            for (int mi = 0; mi < 4; ++mi)
#pragma unroll
                for (int ni = 0; ni < 8; ++ni)
                    acc[mi][ni] = __builtin_amdgcn_mfma_f32_16x16x32_f16(
                        aF[mi], bF[ni], acc[mi][ni], 0, 0, 0);
            __builtin_amdgcn_s_setprio(0);
        }

        // all waves done reading tile t -> safe to overwrite this buffer with tile t+2
        __builtin_amdgcn_s_barrier();
        if (t + 2 < NT) {
            int k0 = (t + 2) * BK;
#pragma unroll
            for (int q = 0; q < 4; ++q)
                __builtin_amdgcn_global_load_lds(
                    (const __attribute__((address_space(1))) void*)(aptr[q] + k0),
                    (__attribute__((address_space(3))) void*)&Ls[cur][0][(q * 512 + wave * 64) * 8],
                    16, 0, 0);
#pragma unroll
            for (int q = 0; q < 4; ++q)
                __builtin_amdgcn_global_load_lds(
                    (const __attribute__((address_space(1))) void*)(bptr[q] + k0),
                    (__attribute__((address_space(3))) void*)&Ls[cur][1][(q * 512 + wave * 64) * 8],
                    16, 0, 0);
        }
        cur ^= 1;
    }

    // C/D layout: col = lane&15 (B-row within 16-tile), row = quad*4 + reg.
    if (gateblk) {
        if (wc == 1) return;   // junk slice, discard
        // gate logits: C[m][col] = X0h[m].Wgh[col], col < 24 -> G[col][m]
#pragma unroll
        for (int mi = 0; mi < 4; ++mi)
#pragma unroll
            for (int ni = 0; ni < 2; ++ni) {
                int col = ni * 16 + mlane;
                if (col < NP) {
#pragma unroll
                    for (int j = 0; j < 4; ++j) {
                        int m = wm * 64 + mi * 16 + quad * 4 + j;
                        G[(size_t)col * BDIM + (m0 + m)] = acc[mi][ni][j];
                    }
                }
            }
    } else {
        const int p = 2 * by + wc;
        // PU col r at ni=r/16, PV at ni+4 (same lane). T[p][m] = sum_r PU*PV.
#pragma unroll
        for (int mi = 0; mi < 4; ++mi) {
#pragma unroll
            for (int j = 0; j < 4; ++j) {
                float tp = 0.f;
#pragma unroll
                for (int ni = 0; ni < 4; ++ni)
                    tp += acc[mi][ni][j] * acc[mi][ni + 4][j];
                tp += __shfl_xor(tp, 1);
                tp += __shfl_xor(tp, 2);
                tp += __shfl_xor(tp, 4);
                tp += __shfl_xor(tp, 8);
                if (mlane == 0) {
                    int m = wm * 64 + mi * 16 + quad * 4 + j;
                    T[(size_t)p * BDIM + (m0 + m)] = tp;
                }
            }
        }
    }
}

// ---------------- per-row scalar recurrence + scaled write-out (reads X0h f16) ----------------
__global__ void epilogue_kernel(const _Float16* __restrict__ X0h,
                                const float* __restrict__ T,
                                const float* __restrict__ G,
                                const float* __restrict__ bg,
                                float* __restrict__ out) {
    __shared__ float s_sh[16];
    const int b0 = blockIdx.x * 16;
    const int tid = (int)threadIdx.x;
    if (tid < 16) {
        int b = b0 + tid;
        float s = 1.f;
#pragma unroll
        for (int l = 0; l < LNUM; ++l) {
            float logit[ENUM];
            float mx = -1e30f;
#pragma unroll
            for (int e = 0; e < ENUM; ++e) {
                int j = l * ENUM + e;
                float g = s * G[(size_t)j * BDIM + b] + bg[j];
                logit[e] = g;
                mx = fmaxf(mx, g);
            }
            float den = 0.f, num = 0.f;
            float s2 = s * s;
#pragma unroll
            for (int e = 0; e < ENUM; ++e) {
                int j = l * ENUM + e;
                float w = __expf(logit[e] - mx);
                den += w;
                num += w * (s2 * T[(size_t)j * BDIM + b]);
            }
            s += num / den;
        }
        s_sh[tid] = s;
    }
    __syncthreads();
    const int nf4 = DDIM / 4;   // 512 float4 per row
    for (int idx = tid; idx < 16 * nf4; idx += 256) {
        int r = idx >> 9;
        int c = idx & (nf4 - 1);
        float s = s_sh[r];
        f16x4 h = ((const f16x4*)(X0h + (size_t)(b0 + r) * DDIM))[c];
        float4 x = { s * (float)h[0], s * (float)h[1], s * (float)h[2], s * (float)h[3] };
        ((float4*)(out + (size_t)(b0 + r) * DDIM))[c] = x;
    }
}

extern "C" void kernel_launch(void* const* d_in, const int* in_sizes, int n_in,
                              void* d_out, int out_size, void* d_ws, size_t ws_size,
                              hipStream_t stream) {
    const float* X0 = (const float*)d_in[0];
    const float* U  = (const float*)d_in[1];
    const float* V  = (const float*)d_in[2];
    const float* Wg = (const float*)d_in[3];
    const float* bg = (const float*)d_in[4];
    float* out = (float*)d_out;

    // workspace layout (~82.9 MB)
    char* ws = (char*)d_ws;
    _Float16* X0h = (_Float16*)ws;                                   // 16384*2048*2 = 67108864
    _Float16* Wh  = (_Float16*)(ws + 67108864ull);                   // 24*128*2048*2 = 12582912
    _Float16* Wgh = (_Float16*)(ws + 79691776ull);                   // 24*2048*2 = 98304
    float* T      = (float*)(ws + 79790080ull);                      // 24*16384*4 = 1572864
    float* G      = (float*)(ws + 81362944ull);                      // 24*16384*4 = 1572864

    cvt_w_kernel<<<dim3((NP * 128 * DDIM / 4) / 256), dim3(256), 0, stream>>>(U, V, Wh);
    cvt_wg_kernel<<<dim3((NP * DDIM / 4) / 256), dim3(256), 0, stream>>>(Wg, Wgh);
    cvt_x_kernel<<<dim3((BDIM * DDIM / 4) / 256), dim3(256), 0, stream>>>(X0, X0h);
    gemm_t_kernel<<<dim3(BDIM / BM, 13), dim3(512), 0, stream>>>(X0h, Wh, Wgh, T, G);
    epilogue_kernel<<<dim3(BDIM / 16), dim3(256), 0, stream>>>(X0h, T, G, bg, out);
}

// Round 4
// 490.452 us; speedup vs baseline: 1.5515x; 1.0037x over previous
//
#include <hip/hip_runtime.h>
#include <hip/hip_bf16.h>

// Problem constants (CrossNetMixFuxiCTR): B=16384, D=2048, L=3, E=8, R=64
#define BDIM 16384
#define DDIM 2048
#define LNUM 3
#define ENUM 8
#define NP 24            // L*E (l,e) pairs

// GEMM tile (8-wave pipelined template)
#define BM 256           // A rows per block
#define BK 64            // f16 k-elements per tile (128 B/row)
#define NT (DDIM / BK)   // 32 K-tiles

typedef _Float16 f16x8 __attribute__((ext_vector_type(8)));
typedef _Float16 f16x4 __attribute__((ext_vector_type(4)));
typedef float f32x4 __attribute__((ext_vector_type(4)));

// ------- convert U,V -> Wh f16 [p=24][128 rows: 64 U then 64 V][D], + Wg -> Wgh -------
// blocks < 6144: U/V conversion; blocks >= 6144: Wg conversion (folded to save a launch)
__global__ void cvt_w_kernel(const float* __restrict__ U, const float* __restrict__ V,
                             const float* __restrict__ Wg,
                             _Float16* __restrict__ Wh, _Float16* __restrict__ Wgh) {
    if (blockIdx.x >= 6144) {
        int f = (int)((blockIdx.x - 6144) * blockDim.x + threadIdx.x);   // 12288 float4
        float4 v = ((const float4*)Wg)[f];
        f16x4 h = { (_Float16)v.x, (_Float16)v.y, (_Float16)v.z, (_Float16)v.w };
        ((f16x4*)Wgh)[f] = h;
        return;
    }
    size_t f = (size_t)blockIdx.x * blockDim.x + threadIdx.x;   // float4 index
    size_t elem = f * 4;
    int d   = (int)(elem & (DDIM - 1));
    int row = (int)((elem >> 11) & 127);   // /2048 % 128
    int p   = (int)(elem >> 18);           // /(2048*128)
    const float* src = (row < 64)
        ? (U + ((size_t)(p * 64 + row) * DDIM + d))
        : (V + ((size_t)(p * 64 + (row - 64)) * DDIM + d));
    float4 v = *(const float4*)src;
    f16x4 h = { (_Float16)v.x, (_Float16)v.y, (_Float16)v.z, (_Float16)v.w };
    ((f16x4*)Wh)[f] = h;
}

// ------- convert X0 f32 -> X0h f16 (memory-bound) -------
__global__ void cvt_x_kernel(const float* __restrict__ X0, _Float16* __restrict__ X0h) {
    size_t f = (size_t)blockIdx.x * blockDim.x + threadIdx.x;   // float4 index
    float4 v = ((const float4*)X0)[f];
    f16x4 h = { (_Float16)v.x, (_Float16)v.y, (_Float16)v.z, (_Float16)v.w };
    ((f16x4*)X0h)[f] = h;
}

// ---------------- pipelined MFMA GEMM + in-wave bilinear reduction ----------------
// 512 thr = 8 waves (wm = wave>>1 in 0..3, wn = wave&1). Tile: 256 rows x 256 cols
// (= TWO p-slices; slice p = 2*by + wn, 128 cols: 0-63 PU, 64-127 PV).
// Wave (wm,wn): rows [wm*64,+64) x full 128 cols of its slice -> acc[4][8].
// Outer schedule (verified R3): dbuf 128 KiB LDS, 2 K-tiles in flight, vmcnt(8)
// counted wait + 2 raw s_barrier per tile; never drains vmcnt to 0 in main loop.
// NEW (R4): intra-tile 4-quadrant snake (ks0n0, ks0n1, ks1n1, ks1n0) with AHEAD-READS:
// each quadrant's 4-8 ds_read_b128 issue BEFORE the previous quadrant's 16-MFMA cluster,
// so LDS reads fly under MFMA (R3 was read-all-24 then MFMA-all-64 in wave lockstep:
// 768clk LDS + 640clk MFMA serialized -> 45% util ceiling, matching measured 40%).
// setprio(1) per MFMA cluster (T5 - now has read/MFMA role diversity to arbitrate).
// LDS swizzle (unchanged): 16B chunk c of row r stored at c ^ (r&7); applied on the
// pre-swizzled GLOBAL source address (linear LDS dest) and on the ds_read addr.
// by == 12 is the GATE block: wn==0 computes G = X0h . Wgh^T (cols 0..23), wn==1 junk.
__global__ __launch_bounds__(512, 2) void gemm_t_kernel(
    const _Float16* __restrict__ Ah,   // [BDIM][DDIM] f16
    const _Float16* __restrict__ Bh,   // [NP][128][DDIM] f16
    const _Float16* __restrict__ Wgh,  // [NP][DDIM] f16 (gate vectors)
    float* __restrict__ T,             // [NP][BDIM]
    float* __restrict__ G)             // [NP][BDIM] gate logits (f32 accum)
{
    const int by   = blockIdx.y;          // 0..11 slice pairs, 12 = gate
    const int m0   = blockIdx.x * BM;
    const int tid  = (int)threadIdx.x;
    const int wave = tid >> 6;
    const int lane = tid & 63;
    const int wm   = wave >> 1;           // 0..3 row quadrant
    const int wn   = wave & 1;            // 0/1 slice within pair
    const int mlane = lane & 15;
    const int quad  = lane >> 4;
    const bool gateblk = (by == 12);

    // [buf][A/B][256 rows * 64 f16] = 128 KiB
    __shared__ _Float16 Ls[2][2][BM * BK];

    // ---- per-thread staging source pointers (pre-swizzled global addresses) ----
    const _Float16* aptr[4];
    const _Float16* bptr[4];
#pragma unroll
    for (int q = 0; q < 4; ++q) {
        int idx = q * 512 + tid;          // 16B-chunk index 0..2047
        int row = idx >> 3;               // 0..255
        int c   = idx & 7;
        int col = ((c ^ (row & 7)) * 8);  // swizzled f16 column within the 64-wide tile
        aptr[q] = Ah + (size_t)(m0 + row) * DDIM + col;
        int s = row >> 7;                 // which slice of the pair
        int brow = row & 127;
        const _Float16* base;
        int br;
        if (gateblk) {
            base = Wgh;
            br = (s == 0 && brow < NP) ? brow : (brow & 15);   // keep addresses valid
        } else {
            base = Bh + (size_t)(2 * by + s) * 128 * DDIM;
            br = brow;
        }
        bptr[q] = base + (size_t)br * DDIM + col;
    }

    f32x4 acc[4][8];
#pragma unroll
    for (int i = 0; i < 4; ++i)
#pragma unroll
        for (int j = 0; j < 8; ++j) acc[i][j] = (f32x4){0.f, 0.f, 0.f, 0.f};

    // ---- prologue: stage tiles 0 and 1 ----
#pragma unroll
    for (int tt = 0; tt < 2; ++tt) {
#pragma unroll
        for (int q = 0; q < 4; ++q)
            __builtin_amdgcn_global_load_lds(
                (const __attribute__((address_space(1))) void*)(aptr[q] + tt * BK),
                (__attribute__((address_space(3))) void*)&Ls[tt][0][(q * 512 + wave * 64) * 8],
                16, 0, 0);
#pragma unroll
        for (int q = 0; q < 4; ++q)
            __builtin_amdgcn_global_load_lds(
                (const __attribute__((address_space(1))) void*)(bptr[q] + tt * BK),
                (__attribute__((address_space(3))) void*)&Ls[tt][1][(q * 512 + wave * 64) * 8],
                16, 0, 0);
    }

    int cur = 0;
    for (int t = 0; t < NT; ++t) {
        // own tile-t loads landed (tile t+1's 8 stay in flight); barrier -> block-wide
        if (t < NT - 1) asm volatile("s_waitcnt vmcnt(8)" ::: "memory");
        else            asm volatile("s_waitcnt vmcnt(0)" ::: "memory");
        __builtin_amdgcn_s_barrier();

        const _Float16* Asc = &Ls[cur][0][0];
        const _Float16* Bsc = &Ls[cur][1][0];

        f16x8 a0[4], a1[4], bx[4], by8[4];
        // q0 reads: A ks0 (4) + B ks0 n0-3 (4)
#pragma unroll
        for (int mi = 0; mi < 4; ++mi) {
            int row = wm * 64 + mi * 16 + mlane;
            a0[mi] = *(const f16x8*)&Asc[row * BK + ((quad ^ (row & 7)) * 8)];
        }
#pragma unroll
        for (int ni = 0; ni < 4; ++ni) {
            int row = wn * 128 + ni * 16 + mlane;
            bx[ni] = *(const f16x8*)&Bsc[row * BK + ((quad ^ (row & 7)) * 8)];
        }
        // q1 ahead-reads: B ks0 n4-7 (4)
#pragma unroll
        for (int ni = 0; ni < 4; ++ni) {
            int row = wn * 128 + (ni + 4) * 16 + mlane;
            by8[ni] = *(const f16x8*)&Bsc[row * BK + ((quad ^ (row & 7)) * 8)];
        }
        __builtin_amdgcn_s_setprio(1);
#pragma unroll
        for (int mi = 0; mi < 4; ++mi)
#pragma unroll
            for (int ni = 0; ni < 4; ++ni)
                acc[mi][ni] = __builtin_amdgcn_mfma_f32_16x16x32_f16(
                    a0[mi], bx[ni], acc[mi][ni], 0, 0, 0);
        __builtin_amdgcn_s_setprio(0);

        // q2 ahead-reads: A ks1 (4) + B ks1 n0-3 (4) (bx dead after q0 -> reuse)
#pragma unroll
        for (int mi = 0; mi < 4; ++mi) {
            int row = wm * 64 + mi * 16 + mlane;
            a1[mi] = *(const f16x8*)&Asc[row * BK + (((4 + quad) ^ (row & 7)) * 8)];
        }
#pragma unroll
        for (int ni = 0; ni < 4; ++ni) {
            int row = wn * 128 + ni * 16 + mlane;
            bx[ni] = *(const f16x8*)&Bsc[row * BK + (((4 + quad) ^ (row & 7)) * 8)];
        }
        __builtin_amdgcn_s_setprio(1);
#pragma unroll
        for (int mi = 0; mi < 4; ++mi)
#pragma unroll
            for (int ni = 0; ni < 4; ++ni)
                acc[mi][ni + 4] = __builtin_amdgcn_mfma_f32_16x16x32_f16(
                    a0[mi], by8[ni], acc[mi][ni + 4], 0, 0, 0);
        __builtin_amdgcn_s_setprio(0);

        // q3 ahead-reads: B ks1 n4-7 (4) (by8 dead after q1 -> reuse)
#pragma unroll
        for (int ni = 0; ni < 4; ++ni) {
            int row = wn * 128 + (ni + 4) * 16 + mlane;
            by8[ni] = *(const f16x8*)&Bsc[row * BK + (((4 + quad) ^ (row & 7)) * 8)];
        }
        __builtin_amdgcn_s_setprio(1);
#pragma unroll
        for (int mi = 0; mi < 4; ++mi)
#pragma unroll
            for (int ni = 0; ni < 4; ++ni)
                acc[mi][ni] = __builtin_amdgcn_mfma_f32_16x16x32_f16(
                    a1[mi], bx[ni], acc[mi][ni], 0, 0, 0);
        __builtin_amdgcn_s_setprio(0);

        __builtin_amdgcn_s_setprio(1);
#pragma unroll
        for (int mi = 0; mi < 4; ++mi)
#pragma unroll
            for (int ni = 0; ni < 4; ++ni)
                acc[mi][ni + 4] = __builtin_amdgcn_mfma_f32_16x16x32_f16(
                    a1[mi], by8[ni], acc[mi][ni + 4], 0, 0, 0);
        __builtin_amdgcn_s_setprio(0);

        // all waves done reading tile t -> safe to overwrite this buffer with tile t+2
        __builtin_amdgcn_s_barrier();
        if (t + 2 < NT) {
            int k0 = (t + 2) * BK;
#pragma unroll
            for (int q = 0; q < 4; ++q)
                __builtin_amdgcn_global_load_lds(
                    (const __attribute__((address_space(1))) void*)(aptr[q] + k0),
                    (__attribute__((address_space(3))) void*)&Ls[cur][0][(q * 512 + wave * 64) * 8],
                    16, 0, 0);
#pragma unroll
            for (int q = 0; q < 4; ++q)
                __builtin_amdgcn_global_load_lds(
                    (const __attribute__((address_space(1))) void*)(bptr[q] + k0),
                    (__attribute__((address_space(3))) void*)&Ls[cur][1][(q * 512 + wave * 64) * 8],
                    16, 0, 0);
        }
        cur ^= 1;
    }

    // C/D layout: col = lane&15 (B-row within 16-tile), row = quad*4 + reg.
    if (gateblk) {
        if (wn == 1) return;   // junk slice, discard
        // gate logits: C[m][col] = X0h[m].Wgh[col], col < 24 -> G[col][m]
#pragma unroll
        for (int mi = 0; mi < 4; ++mi)
#pragma unroll
            for (int ni = 0; ni < 2; ++ni) {
                int col = ni * 16 + mlane;
                if (col < NP) {
#pragma unroll
                    for (int j = 0; j < 4; ++j) {
                        int m = wm * 64 + mi * 16 + quad * 4 + j;
                        G[(size_t)col * BDIM + (m0 + m)] = acc[mi][ni][j];
                    }
                }
            }
    } else {
        const int p = 2 * by + wn;
        // PU col r at ni=r/16, PV at ni+4 (same lane). T[p][m] = sum_r PU*PV.
#pragma unroll
        for (int mi = 0; mi < 4; ++mi) {
#pragma unroll
            for (int j = 0; j < 4; ++j) {
                float tp = 0.f;
#pragma unroll
                for (int ni = 0; ni < 4; ++ni)
                    tp += acc[mi][ni][j] * acc[mi][ni + 4][j];
                tp += __shfl_xor(tp, 1);
                tp += __shfl_xor(tp, 2);
                tp += __shfl_xor(tp, 4);
                tp += __shfl_xor(tp, 8);
                if (mlane == 0) {
                    int m = wm * 64 + mi * 16 + quad * 4 + j;
                    T[(size_t)p * BDIM + (m0 + m)] = tp;
                }
            }
        }
    }
}

// ---------------- per-row scalar recurrence + scaled write-out (reads X0h f16) ----------------
__global__ void epilogue_kernel(const _Float16* __restrict__ X0h,
                                const float* __restrict__ T,
                                const float* __restrict__ G,
                                const float* __restrict__ bg,
                                float* __restrict__ out) {
    __shared__ float s_sh[16];
    const int b0 = blockIdx.x * 16;
    const int tid = (int)threadIdx.x;
    if (tid < 16) {
        int b = b0 + tid;
        float s = 1.f;
#pragma unroll
        for (int l = 0; l < LNUM; ++l) {
            float logit[ENUM];
            float mx = -1e30f;
#pragma unroll
            for (int e = 0; e < ENUM; ++e) {
                int j = l * ENUM + e;
                float g = s * G[(size_t)j * BDIM + b] + bg[j];
                logit[e] = g;
                mx = fmaxf(mx, g);
            }
            float den = 0.f, num = 0.f;
            float s2 = s * s;
#pragma unroll
            for (int e = 0; e < ENUM; ++e) {
                int j = l * ENUM + e;
                float w = __expf(logit[e] - mx);
                den += w;
                num += w * (s2 * T[(size_t)j * BDIM + b]);
            }
            s += num / den;
        }
        s_sh[tid] = s;
    }
    __syncthreads();
    const int nf4 = DDIM / 4;   // 512 float4 per row
    for (int idx = tid; idx < 16 * nf4; idx += 256) {
        int r = idx >> 9;
        int c = idx & (nf4 - 1);
        float s = s_sh[r];
        f16x4 h = ((const f16x4*)(X0h + (size_t)(b0 + r) * DDIM))[c];
        float4 x = { s * (float)h[0], s * (float)h[1], s * (float)h[2], s * (float)h[3] };
        ((float4*)(out + (size_t)(b0 + r) * DDIM))[c] = x;
    }
}

extern "C" void kernel_launch(void* const* d_in, const int* in_sizes, int n_in,
                              void* d_out, int out_size, void* d_ws, size_t ws_size,
                              hipStream_t stream) {
    const float* X0 = (const float*)d_in[0];
    const float* U  = (const float*)d_in[1];
    const float* V  = (const float*)d_in[2];
    const float* Wg = (const float*)d_in[3];
    const float* bg = (const float*)d_in[4];
    float* out = (float*)d_out;

    // workspace layout (~82.9 MB)
    char* ws = (char*)d_ws;
    _Float16* X0h = (_Float16*)ws;                                   // 16384*2048*2 = 67108864
    _Float16* Wh  = (_Float16*)(ws + 67108864ull);                   // 24*128*2048*2 = 12582912
    _Float16* Wgh = (_Float16*)(ws + 79691776ull);                   // 24*2048*2 = 98304
    float* T      = (float*)(ws + 79790080ull);                      // 24*16384*4 = 1572864
    float* G      = (float*)(ws + 81362944ull);                      // 24*16384*4 = 1572864

    cvt_w_kernel<<<dim3(6144 + 48), dim3(256), 0, stream>>>(U, V, Wg, Wh, Wgh);
    cvt_x_kernel<<<dim3((BDIM * DDIM / 4) / 256), dim3(256), 0, stream>>>(X0, X0h);
    gemm_t_kernel<<<dim3(BDIM / BM, 13), dim3(512), 0, stream>>>(X0h, Wh, Wgh, T, G);
    epilogue_kernel<<<dim3(BDIM / 16), dim3(256), 0, stream>>>(X0h, T, G, bg, out);
}